// Round 1
// baseline (174.095 us; speedup 1.0000x reference)
//
#include <hip/hip_runtime.h>
#include <cstdint>
#include <cstddef>

#define GNPB 16       // nodes per fused block
#define MNPB 16       // rows per gemm tile (== GNPB)
#define GAST 264      // LDS A row stride in elems (528 B) — 2-way max bank aliasing per quarter-wave
#define VP_BLOCKS 16  // 4096 threads pack Vp (64 KB, K=256)

typedef __attribute__((ext_vector_type(8))) short bf16x8;
typedef __attribute__((ext_vector_type(4))) float f32x4;

static __device__ __forceinline__ unsigned short f2bf(float f) {
    unsigned int u = __builtin_bit_cast(unsigned int, f);
    u += 0x7fffu + ((u >> 16) & 1u);
    return (unsigned short)(u >> 16);
}
static __device__ __forceinline__ float bfhi(unsigned int u) { return __builtin_bit_cast(float, u & 0xFFFF0000u); }
static __device__ __forceinline__ float bflo(unsigned int u) { return __builtin_bit_cast(float, u << 16); }
// masked bf16x8 accumulate: m = all-ones keeps, 0 zeroes (bf16 0x0000 == +0.0)
static __device__ __forceinline__ void acc8(float* a, const uint4& v, unsigned m) {
    unsigned x0 = v.x & m, x1 = v.y & m, x2 = v.z & m, x3 = v.w & m;
    a[0] += bflo(x0); a[1] += bfhi(x0); a[2] += bflo(x1); a[3] += bfhi(x1);
    a[4] += bflo(x2); a[5] += bfhi(x2); a[6] += bflo(x3); a[7] += bfhi(x3);
}

// ---------------- Prep: Vp pack (B = [Wg+Ws | Wl], K=256), xb = bf16(x), blkoff ----------------
// Vp layout: element ((g*8 + s)*64 + lane)*8 + j = B1[g*16 + (lane&15)][s*32 + (lane>>4)*8 + j]
__global__ __launch_bounds__(256)
void prep(const float* __restrict__ x, const float* __restrict__ Wg,
          const float* __restrict__ Wl, const float* __restrict__ Ws,
          const int* __restrict__ dst, unsigned short* __restrict__ Vp,
          unsigned short* __restrict__ xb, int* __restrict__ blkoff,
          int total8, int nblk_g, int noffb, int E) {
    const int bx = blockIdx.x, t = threadIdx.x;
    if (bx < VP_BLOCKS) {
        int gid = bx * 256 + t;
        if (gid < 4096) {
            int l = gid & 63, srow = (gid >> 6) & 7, g = gid >> 9;
            int o = g * 16 + (l & 15);
            int k = srow * 32 + (l >> 4) * 8;
            uint4 u;
            if (k < 128) {                     // first K-segment: W1 = Wg + Ws
                const float* pg = Wg + o * 128 + k;
                const float* ps = Ws + o * 128 + k;
                u.x = (unsigned)f2bf(pg[0]+ps[0]) | ((unsigned)f2bf(pg[1]+ps[1]) << 16);
                u.y = (unsigned)f2bf(pg[2]+ps[2]) | ((unsigned)f2bf(pg[3]+ps[3]) << 16);
                u.z = (unsigned)f2bf(pg[4]+ps[4]) | ((unsigned)f2bf(pg[5]+ps[5]) << 16);
                u.w = (unsigned)f2bf(pg[6]+ps[6]) | ((unsigned)f2bf(pg[7]+ps[7]) << 16);
            } else {                           // second K-segment: Wl
                const float* pl = Wl + o * 128 + (k - 128);
                u.x = (unsigned)f2bf(pl[0]) | ((unsigned)f2bf(pl[1]) << 16);
                u.y = (unsigned)f2bf(pl[2]) | ((unsigned)f2bf(pl[3]) << 16);
                u.z = (unsigned)f2bf(pl[4]) | ((unsigned)f2bf(pl[5]) << 16);
                u.w = (unsigned)f2bf(pl[6]) | ((unsigned)f2bf(pl[7]) << 16);
            }
            ((uint4*)Vp)[gid] = u;
        }
    } else if (bx < VP_BLOCKS + noffb) {
        int b = (bx - VP_BLOCKS) * 256 + t;
        if (b < nblk_g) {
            int target = b * GNPB;
            int lo = 0, hi = E;
            while (lo < hi) { int mid = (lo + hi) >> 1; if (dst[mid] < target) lo = mid + 1; else hi = mid; }
            blkoff[b] = lo;
        }
    } else {
        int gid = (bx - VP_BLOCKS - noffb) * 256 + t;
        if (gid < total8) {
            const float4* px = (const float4*)x + (size_t)gid * 2;
            float4 a = px[0], bq = px[1];
            uint4 u;
            u.x = (unsigned)f2bf(a.x)  | ((unsigned)f2bf(a.y)  << 16);
            u.y = (unsigned)f2bf(a.z)  | ((unsigned)f2bf(a.w)  << 16);
            u.z = (unsigned)f2bf(bq.x) | ((unsigned)f2bf(bq.y) << 16);
            u.w = (unsigned)f2bf(bq.z) | ((unsigned)f2bf(bq.w) << 16);
            ((uint4*)xb)[gid] = u;
        }
    }
}

// ---------------- Fused gather + GEMM ----------------
// Block = 16 nodes, 256 threads (4 waves). Phase A: each wave gathers/means 4 nodes
// (16-lane x 16B layout, 8 row-loads in flight) straight into the LDS A-panel M slots.
// Phase B: one barrier, then K=256 MFMA over [xb | M] @ [Wg+Ws | Wl]^T, ELU epilogue.
// deg==0 rows get M=0 -> x@(Wg+Ws) (wrong); degfix overwrites them afterwards.
__global__ __launch_bounds__(256, 5)
void fused(const unsigned short* __restrict__ xb, const int* __restrict__ src,
           const int* __restrict__ deg, const int* __restrict__ blkoff,
           const unsigned short* __restrict__ Vp, const float* __restrict__ bias,
           float* __restrict__ out, int N) {
    __shared__ __align__(16) unsigned short As[MNPB * GAST];
    const int t = threadIdx.x, wv = t >> 6, lane = t & 63;
    const int c = lane & 15, p = lane >> 4;
    const int base = blockIdx.x * GNPB;

    // stage-load own xb rows early; LDS write deferred to just before the barrier
    const int srow = t >> 4, sch = t & 15;
    int sgrow = base + srow; if (sgrow > N - 1) sgrow = N - 1;
    const uint4 sval = *(const uint4*)(xb + (size_t)sgrow * 128 + sch * 8);

    // per-block degrees + exclusive prefix (every wave redundantly, no barrier)
    int dg16 = 0;
    if (lane < 16 && base + lane < N) dg16 = deg[base + lane];
    int incl = dg16;
#pragma unroll
    for (int off = 1; off < 16; off <<= 1) {
        int v = __shfl_up(incl, off, 64);
        if (lane >= off) incl += v;
    }
    const int blk_s = blkoff[blockIdx.x];

    const uint4* x4 = (const uint4*)xb;
#pragma unroll 1
    for (int i = 0; i < 4; ++i) {
        const int j = (wv << 2) | i;                  // local row handled by this wave
        const int d = __shfl(dg16, j, 64);
        const int s = blk_s + __shfl(incl, j, 64) - d;
        float a[8] = {0,0,0,0,0,0,0,0};
        if (d > 0) {
            int idx = 0;
            if (lane < d) idx = src[s + lane];        // one coalesced shot, d <= 32
            int r0 = __shfl(idx, p, 64),      r1 = __shfl(idx, p + 4, 64);
            int r2 = __shfl(idx, p + 8, 64),  r3 = __shfl(idx, p + 12, 64);
            uint4 v0 = x4[(size_t)r0 * 16 + c], v1 = x4[(size_t)r1 * 16 + c];
            uint4 v2 = x4[(size_t)r2 * 16 + c], v3 = x4[(size_t)r3 * 16 + c];
            uint4 v4, v5, v6, v7;
            const bool two = (d > 16);
            if (two) {                                // second batch issued before any accumulate
                int e = 16 + p;
                int r4 = __shfl(idx, e, 64),      r5 = __shfl(idx, e + 4, 64);
                int r6 = __shfl(idx, e + 8, 64),  r7 = __shfl(idx, e + 12, 64);
                v4 = x4[(size_t)r4 * 16 + c]; v5 = x4[(size_t)r5 * 16 + c];
                v6 = x4[(size_t)r6 * 16 + c]; v7 = x4[(size_t)r7 * 16 + c];
            }
            float b[8] = {0,0,0,0,0,0,0,0};
            acc8(a, v0, (p      < d) ? ~0u : 0u);
            acc8(b, v1, (p + 4  < d) ? ~0u : 0u);
            acc8(a, v2, (p + 8  < d) ? ~0u : 0u);
            acc8(b, v3, (p + 12 < d) ? ~0u : 0u);
            if (two) {
                int e = 16 + p;
                acc8(a, v4, (e      < d) ? ~0u : 0u);
                acc8(b, v5, (e + 4  < d) ? ~0u : 0u);
                acc8(a, v6, (e + 8  < d) ? ~0u : 0u);
                acc8(b, v7, (e + 12 < d) ? ~0u : 0u);
            }
#pragma unroll
            for (int q = 0; q < 8; ++q) a[q] += b[q];
#pragma unroll
            for (int q = 0; q < 8; ++q) {
                a[q] += __shfl_xor(a[q], 16, 64);
                a[q] += __shfl_xor(a[q], 32, 64);
            }
        }
        if (p == 0) {                                 // write mean row into A-panel M slot
            float inv = (d > 0) ? 1.0f / (float)d : 0.0f;
            uint4 u;
            u.x = (unsigned)f2bf(a[0]*inv) | ((unsigned)f2bf(a[1]*inv) << 16);
            u.y = (unsigned)f2bf(a[2]*inv) | ((unsigned)f2bf(a[3]*inv) << 16);
            u.z = (unsigned)f2bf(a[4]*inv) | ((unsigned)f2bf(a[5]*inv) << 16);
            u.w = (unsigned)f2bf(a[6]*inv) | ((unsigned)f2bf(a[7]*inv) << 16);
            *(uint4*)(As + j * GAST + 128 + c * 8) = u;
        }
    }

    // deferred xb-panel write + B prefetch (global, independent of LDS), then one barrier
    *(uint4*)(As + srow * GAST + sch * 8) = sval;
    const int g0 = 2 * wv, g1 = 2 * wv + 1;
    const bf16x8* VB = (const bf16x8*)Vp;
    bf16x8 b0 = VB[(g0 * 8) * 64 + lane];
    bf16x8 b1 = VB[(g1 * 8) * 64 + lane];
    __syncthreads();

    f32x4 acc0 = (f32x4){0.f, 0.f, 0.f, 0.f};
    f32x4 acc1 = (f32x4){0.f, 0.f, 0.f, 0.f};
#pragma unroll
    for (int s2 = 0; s2 < 8; ++s2) {
        int sn = (s2 + 1 < 8) ? s2 + 1 : 0;          // branchless prefetch
        bf16x8 n0 = VB[(g0 * 8 + sn) * 64 + lane];
        bf16x8 n1 = VB[(g1 * 8 + sn) * 64 + lane];
        bf16x8 a0 = *(const bf16x8*)(As + c * GAST + s2 * 32 + p * 8);
        acc0 = __builtin_amdgcn_mfma_f32_16x16x32_bf16(a0, b0, acc0, 0, 0, 0);
        acc1 = __builtin_amdgcn_mfma_f32_16x16x32_bf16(a0, b1, acc1, 0, 0, 0);
        b0 = n0; b1 = n1;
    }

    // epilogue: + bias, ELU, store. C/D: col=lane&15, row=p*4+reg
    const int col0 = g0 * 16 + c, col1 = g1 * 16 + c;
    const float bv0 = bias[col0], bv1 = bias[col1];
#pragma unroll
    for (int reg = 0; reg < 4; ++reg) {
        int grow = base + p * 4 + reg;
        if (grow < N) {
            float v0 = acc0[reg] + bv0;
            float v1 = acc1[reg] + bv1;
            out[(size_t)grow * 128 + col0] = (v0 > 0.f) ? v0 : __expf(v0) - 1.0f;
            out[(size_t)grow * 128 + col1] = (v1 > 0.f) ? v1 : __expf(v1) - 1.0f;
        }
    }
}

// ---------------- degfix: overwrite deg==0 rows with exact f32 elu(x@Wg.T + b) ----------------
// ~3% of nodes. Thread-per-node scan (coalesced deg load), then wave-cooperative row GEMV
// per set ballot bit: lane computes cols {lane, lane+64}. Full f32 -> strictly more accurate
// than the bf16 path it replaces.
__global__ __launch_bounds__(256)
void degfix(const float* __restrict__ x, const float* __restrict__ Wg,
            const float* __restrict__ bias, const int* __restrict__ deg,
            float* __restrict__ out, int N) {
    const int t = threadIdx.x, lane = t & 63;
    const int nb = blockIdx.x * 256 + t;
    int d = 1;
    if (nb < N) d = deg[nb];
    unsigned long long m = __ballot(d == 0);
    const int wbase = blockIdx.x * 256 + ((t >> 6) << 6);
    while (m) {
        int bit = __builtin_ctzll(m);
        m &= m - 1;
        int n = wbase + bit;
        const float* xr = x + (size_t)n * 128;
        const float* w0 = Wg + (size_t)lane * 128;
        const float* w1 = Wg + (size_t)(lane + 64) * 128;
        float a0 = 0.f, a1 = 0.f;
#pragma unroll 8
        for (int k = 0; k < 128; k += 4) {
            float4 xv = *(const float4*)(xr + k);
            float4 wa = *(const float4*)(w0 + k);
            float4 wb = *(const float4*)(w1 + k);
            a0 += xv.x * wa.x + xv.y * wa.y + xv.z * wa.z + xv.w * wa.w;
            a1 += xv.x * wb.x + xv.y * wb.y + xv.z * wb.z + xv.w * wb.w;
        }
        a0 += bias[lane]; a1 += bias[lane + 64];
        out[(size_t)n * 128 + lane]      = (a0 > 0.f) ? a0 : __expf(a0) - 1.0f;
        out[(size_t)n * 128 + lane + 64] = (a1 > 0.f) ? a1 : __expf(a1) - 1.0f;
    }
}

extern "C" void kernel_launch(void* const* d_in, const int* in_sizes, int n_in,
                              void* d_out, int out_size, void* d_ws, size_t ws_size,
                              hipStream_t stream) {
    const float* x  = (const float*)d_in[0];
    const float* Wg = (const float*)d_in[1];
    const float* Wl = (const float*)d_in[2];
    const float* Ws = (const float*)d_in[3];
    const float* b  = (const float*)d_in[4];
    const int*   src = (const int*)d_in[5];
    const int*   dst = (const int*)d_in[6];
    const int*   deg = (const int*)d_in[7];
    const int E = in_sizes[5];
    const int N = in_sizes[7];
    float* out = (float*)d_out;

    unsigned short* Vp     = (unsigned short*)d_ws;              // 64 KB (packed B, K=256)
    int*            blkoff = (int*)((char*)d_ws + 65536);        // 32 KB reserved
    unsigned short* xb     = (unsigned short*)((char*)d_ws + 98304);  // 12.8 MB

    const int nblk_g = (N + GNPB - 1) / GNPB;      // 3125
    const int noffb  = (nblk_g + 255) / 256;       // 13
    const int total8 = N * 16;
    const int nconv  = (total8 + 255) / 256;       // 3125

    prep<<<dim3(VP_BLOCKS + noffb + nconv), dim3(256), 0, stream>>>(
        x, Wg, Wl, Ws, dst, Vp, xb, blkoff, total8, nblk_g, noffb, E);
    fused<<<dim3(nblk_g), dim3(256), 0, stream>>>(xb, src, deg, blkoff, Vp, b, out, N);
    degfix<<<dim3((N + 255) / 256), dim3(256), 0, stream>>>(x, Wg, b, deg, out, N);
}